// Round 1
// baseline (147.008 us; speedup 1.0000x reference)
//
#include <hip/hip_runtime.h>

// IoULoss, C=4 over 16x1024x1024 preds(float,int-valued)/labels(int).
// inter[c], cnt_pred[c], cnt_label[c]; union = cp+cl-inter.
// R7: (a) reduce kernel vectorized uint4 + unroll-8 (was 32 scalar
// latency-bound loads/lane ~= 10-12us; now one latency exposure ~2-3us).
// (b) count kernel: plain loads instead of nontemporal (nt was neutral in
// R6; plain can recover L3 residency of the 128MiB inputs vs 256MiB L3).

#define NCLS 4
#define NCNT (3 * NCLS)   // [inter0..3 | cp0..3 | cl0..3]

typedef float vf4 __attribute__((ext_vector_type(4)));
typedef int   vi4 __attribute__((ext_vector_type(4)));

__global__ __launch_bounds__(256) void iou_count_kernel(
    const vf4* __restrict__ preds,
    const vi4* __restrict__ labels,
    unsigned int* __restrict__ partials,   // [NCNT][nblk], counter-major
    int n4)
{
    unsigned int acc_i = 0, acc_p = 0, acc_l = 0;

    const int tid    = blockIdx.x * blockDim.x + threadIdx.x;
    const int stride = gridDim.x * blockDim.x;

    auto proc = [&](float pf, int lv) {
        const int      ip = (int)pf;
        const unsigned tp = 1u << (ip << 3);
        const unsigned tl = 1u << (lv << 3);
        acc_p += tp;
        acc_l += tl;
        acc_i += (ip == lv) ? tl : 0u;
    };
    auto acc4 = [&](const vf4 p, const vi4 l) {
        proc(p.x, l.x); proc(p.y, l.y); proc(p.z, l.z); proc(p.w, l.w);
    };

    int idx = tid;
    // Unroll x4: 8 independent 16B streams in flight before first use.
    for (; idx + 3 * stride < n4; idx += 4 * stride) {
        const vf4 p0 = preds[idx];
        const vf4 p1 = preds[idx + stride];
        const vf4 p2 = preds[idx + 2 * stride];
        const vf4 p3 = preds[idx + 3 * stride];
        const vi4 l0 = labels[idx];
        const vi4 l1 = labels[idx + stride];
        const vi4 l2 = labels[idx + 2 * stride];
        const vi4 l3 = labels[idx + 3 * stride];
        acc4(p0, l0); acc4(p1, l1); acc4(p2, l2); acc4(p3, l3);
    }
    for (; idx < n4; idx += stride)
        acc4(preds[idx], labels[idx]);

    // Split packed-8 into packed-16 pairs (classes {0,2}/{1,3}).
    unsigned pk[6];
    pk[0] = acc_i & 0x00FF00FFu; pk[1] = (acc_i >> 8) & 0x00FF00FFu;
    pk[2] = acc_p & 0x00FF00FFu; pk[3] = (acc_p >> 8) & 0x00FF00FFu;
    pk[4] = acc_l & 0x00FF00FFu; pk[5] = (acc_l >> 8) & 0x00FF00FFu;

#pragma unroll
    for (int k = 0; k < 6; ++k) {
#pragma unroll
        for (int off = 32; off > 0; off >>= 1)
            pk[k] += __shfl_down(pk[k], off);
    }

    __shared__ unsigned int s[4][6];
    const int wave = threadIdx.x >> 6;
    if ((threadIdx.x & 63) == 0) {
#pragma unroll
        for (int k = 0; k < 6; ++k) s[wave][k] = pk[k];
    }
    __syncthreads();

    if (threadIdx.x < 6) {
        const int k = threadIdx.x;
        const unsigned tot = s[0][k] + s[1][k] + s[2][k] + s[3][k];
        const int g = k >> 1, r = k & 1;   // group, low-class parity
        partials[(g * NCLS + r)     * gridDim.x + blockIdx.x] = tot & 0xFFFFu;
        partials[(g * NCLS + r + 2) * gridDim.x + blockIdx.x] = tot >> 16;
    }
}

// One block, 12 waves: wave w sums counter row w via uint4 loads (8 in
// flight per lane at nblk=2048); threads 0..3 finalize.
__global__ __launch_bounds__(768) void iou_reduce_kernel(
    const unsigned int* __restrict__ partials,
    float* __restrict__ out,
    int nblk)
{
    __shared__ unsigned int tot[NCNT];
    const int w    = threadIdx.x >> 6;
    const int lane = threadIdx.x & 63;

    if (w < NCNT) {
        const unsigned int* row = partials + (size_t)w * nblk;
        const uint4* row4 = (const uint4*)row;
        const int n4r = nblk >> 2;

        unsigned s0 = 0, s1 = 0, s2 = 0, s3 = 0;
#pragma unroll 8
        for (int k = lane; k < n4r; k += 64) {
            const uint4 v = row4[k];
            s0 += v.x; s1 += v.y; s2 += v.z; s3 += v.w;
        }
        unsigned sum = (s0 + s1) + (s2 + s3);
        // scalar tail if nblk not a multiple of 4
        for (int k = (n4r << 2) + lane; k < nblk; k += 64)
            sum += row[k];

#pragma unroll
        for (int off = 32; off > 0; off >>= 1)
            sum += __shfl_down(sum, off);
        if (lane == 0) tot[w] = sum;
    }
    __syncthreads();

    if (threadIdx.x < NCLS) {
        const int c = threadIdx.x;
        const float inter = (float)tot[c];
        const float uni   = (float)tot[NCLS + c] + (float)tot[2 * NCLS + c]
                            - (float)tot[c];
        const float iou   = (uni == 0.0f) ? 1.0f : (inter / uni);
        out[c] = 1.0f - 100.0f * iou;
    }
}

extern "C" void kernel_launch(void* const* d_in, const int* in_sizes, int n_in,
                              void* d_out, int out_size, void* d_ws, size_t ws_size,
                              hipStream_t stream) {
    const vf4* preds  = (const vf4*)d_in[0];
    const vi4* labels = (const vi4*)d_in[1];
    unsigned int* partials = (unsigned int*)d_ws;
    float* out = (float*)d_out;

    const int n  = in_sizes[0];      // 16*1024*1024
    const int n4 = n / 4;

    int nblk = 2048;
    const int cap = (int)(ws_size / (NCNT * sizeof(unsigned int)));
    if (cap < nblk) nblk = cap & ~3;
    if (nblk < 1) nblk = 1;

    iou_count_kernel<<<nblk, 256, 0, stream>>>(preds, labels, partials, n4);
    iou_reduce_kernel<<<1, 768, 0, stream>>>(partials, out, nblk);
}